// Round 1
// baseline (69.686 us; speedup 1.0000x reference)
//
#include <hip/hip_runtime.h>
#include <math.h>

#define EMB_DIM 500
#define TWO_D 1000
#define NUM_ENTITIES 14541
#define B_SIZE 16
#define GAMMA_F 12.0f
// PI / ((GAMMA + 2) / EMB_DIM) = pi / 0.028
#define PHASE_SCALE 112.19973762820692f

// ---------------------------------------------------------------------------
// Kernel 1: precompute rotated head embeddings into workspace.
// rot layout: re at [b*500 + d], im at [8000 + b*500 + d]
// ---------------------------------------------------------------------------
__global__ __launch_bounds__(256) void rot_precompute(
    const int* __restrict__ all_h, const int* __restrict__ all_r,
    const float* __restrict__ eemb, const float* __restrict__ remb,
    float* __restrict__ rot)
{
    int i = blockIdx.x * 256 + threadIdx.x;
    if (i >= B_SIZE * EMB_DIM) return;
    int b = i / EMB_DIM;
    int d = i - b * EMB_DIM;
    int h = all_h[b];
    int r = all_r[b];
    float re_h = eemb[h * TWO_D + d];
    float im_h = eemb[h * TWO_D + EMB_DIM + d];
    float ph = remb[r * EMB_DIM + d] * PHASE_SCALE;
    float s, c;
    sincosf(ph, &s, &c);
    rot[i]                      = re_h * c - im_h * s;  // re_rot
    rot[B_SIZE * EMB_DIM + i]   = re_h * s + im_h * c;  // im_rot
}

// ---------------------------------------------------------------------------
// Kernel 2: score all entities. One block = 16 entities (4 per wave).
// Rot table (64 KB) staged in LDS; entity rows streamed from global exactly
// once (coalesced: lane l reads d = l + 64*it).
// ---------------------------------------------------------------------------
__global__ __launch_bounds__(256) void rotate_score(
    const float* __restrict__ eemb,
    const float* __restrict__ rot,       // may be nullptr -> compute in-kernel
    const int* __restrict__ all_h, const int* __restrict__ all_r,
    const float* __restrict__ remb,
    float* __restrict__ out)
{
    __shared__ float lds[2 * B_SIZE * EMB_DIM];  // 64000 bytes

    int tid = threadIdx.x;

    if (rot != nullptr) {
        const float4* src = (const float4*)rot;
        float4* dst = (float4*)lds;
        const int n4 = 2 * B_SIZE * EMB_DIM / 4;  // 4000
        for (int i = tid; i < n4; i += 256) dst[i] = src[i];
    } else {
        for (int i = tid; i < B_SIZE * EMB_DIM; i += 256) {
            int b = i / EMB_DIM;
            int d = i - b * EMB_DIM;
            int h = all_h[b];
            int r = all_r[b];
            float re_h = eemb[h * TWO_D + d];
            float im_h = eemb[h * TWO_D + EMB_DIM + d];
            float ph = remb[r * EMB_DIM + d] * PHASE_SCALE;
            float s, c;
            sincosf(ph, &s, &c);
            lds[i]                    = re_h * c - im_h * s;
            lds[B_SIZE * EMB_DIM + i] = re_h * s + im_h * c;
        }
    }
    __syncthreads();

    int wave = tid >> 6;
    int lane = tid & 63;
    int e0 = blockIdx.x * 16 + wave * 4;

    int e[4];
#pragma unroll
    for (int k = 0; k < 4; ++k) {
        int ek = e0 + k;
        e[k] = (ek < NUM_ENTITIES) ? ek : (NUM_ENTITIES - 1);
    }

    float acc[4][16];
#pragma unroll
    for (int k = 0; k < 4; ++k)
#pragma unroll
        for (int b = 0; b < 16; ++b) acc[k][b] = 0.0f;

    for (int d = lane; d < EMB_DIM; d += 64) {
        float rre[16], rim[16];
#pragma unroll
        for (int b = 0; b < 16; ++b) {
            rre[b] = lds[b * EMB_DIM + d];
            rim[b] = lds[B_SIZE * EMB_DIM + b * EMB_DIM + d];
        }
#pragma unroll
        for (int k = 0; k < 4; ++k) {
            int base = e[k] * TWO_D + d;
            float ret = eemb[base];
            float imt = eemb[base + EMB_DIM];
#pragma unroll
            for (int b = 0; b < 16; ++b) {
                float dre = rre[b] - ret;
                float dim = rim[b] - imt;
                acc[k][b] += __builtin_amdgcn_sqrtf(dre * dre + dim * dim);
            }
        }
    }

    // Reduce each of the 64 (k,b) partials across the 64 lanes.
#pragma unroll
    for (int k = 0; k < 4; ++k) {
#pragma unroll
        for (int b = 0; b < 16; ++b) {
            float v = acc[k][b];
            v += __shfl_xor(v, 32);
            v += __shfl_xor(v, 16);
            v += __shfl_xor(v, 8);
            v += __shfl_xor(v, 4);
            v += __shfl_xor(v, 2);
            v += __shfl_xor(v, 1);
            if (lane == 0 && (e0 + k) < NUM_ENTITIES) {
                out[b * NUM_ENTITIES + (e0 + k)] = GAMMA_F - v;
            }
        }
    }
}

extern "C" void kernel_launch(void* const* d_in, const int* in_sizes, int n_in,
                              void* d_out, int out_size, void* d_ws, size_t ws_size,
                              hipStream_t stream) {
    const int*   all_h = (const int*)d_in[0];
    const int*   all_r = (const int*)d_in[1];
    const float* eemb  = (const float*)d_in[2];
    const float* remb  = (const float*)d_in[3];
    float* out = (float*)d_out;

    float* rot = nullptr;
    const size_t rot_bytes = (size_t)(2 * B_SIZE * EMB_DIM) * sizeof(float);
    if (ws_size >= rot_bytes) {
        rot = (float*)d_ws;
        rot_precompute<<<(B_SIZE * EMB_DIM + 255) / 256, 256, 0, stream>>>(
            all_h, all_r, eemb, remb, rot);
    }

    int nblocks = (NUM_ENTITIES + 15) / 16;  // 909
    rotate_score<<<nblocks, 256, 0, stream>>>(eemb, rot, all_h, all_r, remb, out);
}

// Round 2
// 39.832 us; speedup vs baseline: 1.7495x; 1.7495x over previous
//
#include <hip/hip_runtime.h>
#include <hip/hip_fp16.h>
#include <math.h>

#define EMB_DIM 500
#define TWO_D 1000
#define D4 125                 // float4 groups per half-row (500/4)
#define ROW_F4 250             // float4 per entity row (1000/4)
#define NUM_ENTITIES 14541
#define B_SIZE 16
#define GAMMA_F 12.0f
// PI / ((GAMMA + 2) / EMB_DIM) = pi / 0.028
#define PHASE_SCALE 112.19973762820692f
#define ROT_HALFS (B_SIZE * D4 * 8)   // 16000 halfs = 32000 B

// ---------------------------------------------------------------------------
// Kernel 1: precompute rotated head embeddings as fp16, interleaved layout
// rot[b][d4][0..3] = re(4*d4 .. 4*d4+3), rot[b][d4][4..7] = im(...)
// so the main kernel reads one float4 (8 halfs) per (b, d4).
// ---------------------------------------------------------------------------
__global__ __launch_bounds__(256) void rot_precompute(
    const int* __restrict__ all_h, const int* __restrict__ all_r,
    const float* __restrict__ eemb, const float* __restrict__ remb,
    __half* __restrict__ rot)
{
    int i = blockIdx.x * 256 + threadIdx.x;
    if (i >= B_SIZE * EMB_DIM) return;
    int b = i / EMB_DIM;
    int d = i - b * EMB_DIM;
    int h = all_h[b];
    int r = all_r[b];
    float re_h = eemb[h * TWO_D + d];
    float im_h = eemb[h * TWO_D + EMB_DIM + d];
    float ph = remb[r * EMB_DIM + d] * PHASE_SCALE;
    float s, c;
    sincosf(ph, &s, &c);
    int base = ((b * D4 + (d >> 2)) << 3) + (d & 3);
    rot[base]     = __float2half(re_h * c - im_h * s);  // re_rot
    rot[base + 4] = __float2half(re_h * s + im_h * c);  // im_rot
}

// ---------------------------------------------------------------------------
// Kernel 2: one block = 16 entities (4 per wave). Rot table (32 KB fp16) in
// LDS; entity rows streamed via float4 (lane l owns d4 = l, l+64).
// Epilogue: halving butterfly -> lane L holds full sum of acc[L].
// ---------------------------------------------------------------------------
__global__ __launch_bounds__(256, 4) void rotate_score(
    const float* __restrict__ eemb,
    const __half* __restrict__ rot,      // nullptr -> compute in-kernel
    const int* __restrict__ all_h, const int* __restrict__ all_r,
    const float* __restrict__ remb,
    float* __restrict__ out)
{
    __shared__ __half lrot[ROT_HALFS];   // 32000 bytes

    const int tid = threadIdx.x;

    if (rot != nullptr) {
        const float4* src = (const float4*)rot;
        float4* dst = (float4*)lrot;
        for (int i = tid; i < ROT_HALFS / 8; i += 256) dst[i] = src[i];
    } else {
        for (int i = tid; i < B_SIZE * EMB_DIM; i += 256) {
            int b = i / EMB_DIM;
            int d = i - b * EMB_DIM;
            int h = all_h[b];
            int r = all_r[b];
            float re_h = eemb[h * TWO_D + d];
            float im_h = eemb[h * TWO_D + EMB_DIM + d];
            float ph = remb[r * EMB_DIM + d] * PHASE_SCALE;
            float s, c;
            sincosf(ph, &s, &c);
            int base = ((b * D4 + (d >> 2)) << 3) + (d & 3);
            lrot[base]     = __float2half(re_h * c - im_h * s);
            lrot[base + 4] = __float2half(re_h * s + im_h * c);
        }
    }
    __syncthreads();

    const int lane = tid & 63;
    const int wave = tid >> 6;
    const int e0 = blockIdx.x * 16 + wave * 4;

    int e[4];
#pragma unroll
    for (int k = 0; k < 4; ++k) {
        int ek = e0 + k;
        e[k] = (ek < NUM_ENTITIES) ? ek : (NUM_ENTITIES - 1);
    }

    float v[64];                         // acc[k][b] flattened: idx = k*16+b
#pragma unroll
    for (int i = 0; i < 64; ++i) v[i] = 0.0f;

    const float4* lrot4 = (const float4*)lrot;
    const float4* ee4 = (const float4*)eemb;

#pragma unroll
    for (int it = 0; it < 2; ++it) {
        const int d4 = it * 64 + lane;
        if (d4 < D4) {
            float4 tre[4], tim[4];
#pragma unroll
            for (int k = 0; k < 4; ++k) {
                int rb = e[k] * ROW_F4;
                tre[k] = ee4[rb + d4];
                tim[k] = ee4[rb + D4 + d4];
            }
#pragma unroll
            for (int b = 0; b < 16; ++b) {
                float4 rv = lrot4[b * D4 + d4];
                __half2 p0 = __builtin_bit_cast(__half2, rv.x);
                __half2 p1 = __builtin_bit_cast(__half2, rv.y);
                __half2 p2 = __builtin_bit_cast(__half2, rv.z);
                __half2 p3 = __builtin_bit_cast(__half2, rv.w);
                float rre0 = __low2float(p0), rre1 = __high2float(p0);
                float rre2 = __low2float(p1), rre3 = __high2float(p1);
                float rim0 = __low2float(p2), rim1 = __high2float(p2);
                float rim2 = __low2float(p3), rim3 = __high2float(p3);
#pragma unroll
                for (int k = 0; k < 4; ++k) {
                    float dre, dim;
                    dre = rre0 - tre[k].x; dim = rim0 - tim[k].x;
                    v[k * 16 + b] += __builtin_amdgcn_sqrtf(dre * dre + dim * dim);
                    dre = rre1 - tre[k].y; dim = rim1 - tim[k].y;
                    v[k * 16 + b] += __builtin_amdgcn_sqrtf(dre * dre + dim * dim);
                    dre = rre2 - tre[k].z; dim = rim2 - tim[k].z;
                    v[k * 16 + b] += __builtin_amdgcn_sqrtf(dre * dre + dim * dim);
                    dre = rre3 - tre[k].w; dim = rim3 - tim[k].w;
                    v[k * 16 + b] += __builtin_amdgcn_sqrtf(dre * dre + dim * dim);
                }
            }
        }
    }

    // Halving butterfly: each stage exchanges complementary halves with
    // lane^m; after 6 stages lane L holds the full 64-lane sum of v[L].
#pragma unroll
    for (int m = 32; m >= 1; m >>= 1) {
        const bool hi = (lane & m) != 0;
#pragma unroll
        for (int i = 0; i < m; ++i) {
            float give = hi ? v[i] : v[m + i];
            float keep = hi ? v[m + i] : v[i];
            v[i] = keep + __shfl_xor(give, m, 64);
        }
    }

    const int kk = lane >> 4;
    const int bb = lane & 15;
    const int ee = e0 + kk;
    if (ee < NUM_ENTITIES) out[bb * NUM_ENTITIES + ee] = GAMMA_F - v[0];
}

extern "C" void kernel_launch(void* const* d_in, const int* in_sizes, int n_in,
                              void* d_out, int out_size, void* d_ws, size_t ws_size,
                              hipStream_t stream) {
    const int*   all_h = (const int*)d_in[0];
    const int*   all_r = (const int*)d_in[1];
    const float* eemb  = (const float*)d_in[2];
    const float* remb  = (const float*)d_in[3];
    float* out = (float*)d_out;

    __half* rot = nullptr;
    const size_t rot_bytes = (size_t)ROT_HALFS * sizeof(__half);
    if (ws_size >= rot_bytes) {
        rot = (__half*)d_ws;
        rot_precompute<<<(B_SIZE * EMB_DIM + 255) / 256, 256, 0, stream>>>(
            all_h, all_r, eemb, remb, rot);
    }

    int nblocks = (NUM_ENTITIES + 15) / 16;  // 909
    rotate_score<<<nblocks, 256, 0, stream>>>(eemb, rot, all_h, all_r, remb, out);
}